// Round 3
// baseline (149.420 us; speedup 1.0000x reference)
//
#include <hip/hip_runtime.h>

#define B_    16
#define N_    4096
#define S_    1024
#define K_    32
#define DIN_  64
#define DINC_ 67
#define DOUT_ 64

#define W1P 69   // LDS row stride for w1: 69 % 32 = 5 (odd) -> 2-way aliasing only (free)
#define W2P 65   // 65 % 32 = 1 -> 2-way only

// ---------------------------------------------------------------------------
// Kernel 1: per-row projection.
//   proj[row,c] = bias[c] + dot(xc_row, w1[c,:]) + use_x * dot(x_row, w2[c,:])
//   xp[row,c]   = dot(x_row, w2[c,:])
// wave = 64 lanes = 64 output channels.
// Weights: global -> LDS (coalesced, once per block) -> VGPR (conflict-free
// strides), then PINNED via asm so the compiler cannot rematerialize the
// loads inside the row loop (round-2 failure mode: VGPR_Count=76, weights
// re-fetched per row at 64 L1-lines/instr).
// Activations: wave-uniform pointers (readfirstlane) -> scalar s_loads.
// ---------------------------------------------------------------------------
__global__ __launch_bounds__(256, 1) void proj_kernel(
    const float* __restrict__ x, const float* __restrict__ xcm,
    const float* __restrict__ w1, const float* __restrict__ w2,
    const float* __restrict__ bias, const int* __restrict__ use_x_p,
    float* __restrict__ proj, float* __restrict__ xp)
{
    __shared__ float lw1[DOUT_ * W1P];
    __shared__ float lw2[DOUT_ * W2P];

    // cooperative coalesced stage of both weight matrices into LDS
    for (int i = threadIdx.x; i < DOUT_ * DINC_; i += 256)
        lw1[(i / DINC_) * W1P + (i % DINC_)] = w1[i];
    for (int i = threadIdx.x; i < DOUT_ * DIN_; i += 256)
        lw2[(i >> 6) * W2P + (i & 63)] = w2[i];
    __syncthreads();

    const int lane   = threadIdx.x & 63;
    const int wave   = (blockIdx.x * blockDim.x + threadIdx.x) >> 6;
    const int nwaves = (gridDim.x * blockDim.x) >> 6;
    const int ux     = use_x_p[0];

    float W1[DINC_];
#pragma unroll
    for (int j = 0; j < DINC_; ++j) W1[j] = lw1[lane * W1P + j];
    float W2[DIN_];
#pragma unroll
    for (int j = 0; j < DIN_; ++j) W2[j] = lw2[lane * W2P + j];
    // pin: forces the 131 weights to live in VGPRs across the row loop
#pragma unroll
    for (int j = 0; j < DINC_; ++j) asm volatile("" : "+v"(W1[j]));
#pragma unroll
    for (int j = 0; j < DIN_; ++j) asm volatile("" : "+v"(W2[j]));
    const float bv = bias[lane];

    const int rows = B_ * N_;
    for (int row = wave; row < rows; row += nwaves) {
        const int row_u = __builtin_amdgcn_readfirstlane(row);
        const float* xc_row = xcm + (size_t)row_u * DINC_;
        const float* x_row  = x   + (size_t)row_u * DIN_;

        // 4-way split accumulators break the dependent-FMA chain
        float a0 = 0.f, a1 = 0.f, a2 = 0.f, a3 = 0.f;
#pragma unroll
        for (int j = 0; j < 64; j += 4) {
            a0 += xc_row[j + 0] * W1[j + 0];
            a1 += xc_row[j + 1] * W1[j + 1];
            a2 += xc_row[j + 2] * W1[j + 2];
            a3 += xc_row[j + 3] * W1[j + 3];
        }
        a0 += xc_row[64] * W1[64];
        a1 += xc_row[65] * W1[65];
        a2 += xc_row[66] * W1[66];
        const float s1 = ((a0 + a1) + (a2 + a3)) + bv;

        float b0 = 0.f, b1 = 0.f, b2 = 0.f, b3 = 0.f;
#pragma unroll
        for (int j = 0; j < 64; j += 4) {
            b0 += x_row[j + 0] * W2[j + 0];
            b1 += x_row[j + 1] * W2[j + 1];
            b2 += x_row[j + 2] * W2[j + 2];
            b3 += x_row[j + 3] * W2[j + 3];
        }
        const float s2 = (b0 + b1) + (b2 + b3);

        const size_t o = (size_t)row_u * DOUT_ + lane;
        xp[o]   = s2;
        proj[o] = ux ? (s1 + s2) : s1;
    }
}

// ---------------------------------------------------------------------------
// Kernel 2: gather + masked max + center subtraction, float4-wide,
// XCD-swizzled: blockIdx%8 selects the XCD (round-robin dispatch heuristic);
// each XCD handles exactly 2 batches -> its 4MB proj+xp slab fits the 4MiB
// per-XCD L2, turning the random row gathers into L2 hits.
// ---------------------------------------------------------------------------
__global__ __launch_bounds__(256) void gather_max_kernel(
    const int* __restrict__ indexes, const float* __restrict__ proj,
    const float* __restrict__ xp, const int* __restrict__ use_x_p,
    float* __restrict__ out)
{
    const int lane = threadIdx.x & 63;
    const int xcd  = blockIdx.x & 7;
    const int tb   = blockIdx.x >> 3;
    const int pair = xcd * ((B_ * S_) / 8) + tb * 4 + (threadIdx.x >> 6);
    const int b    = pair >> 10;   // S_ = 1024
    const int q    = lane >> 4;
    const int li   = lane & 15;
    const int ux   = use_x_p[0];

    const int* idxp  = indexes + (size_t)pair * K_;
    const int  myidx = idxp[lane & 31];          // lane k<32 holds idx[k]

    const float* projb = proj + (size_t)b * N_ * DOUT_;
    const float  NEG   = -__builtin_inff();

    float mx = NEG, my = NEG, mz = NEG, mw = NEG;
#pragma unroll
    for (int t = 0; t < 8; ++t) {
        const int k   = q * 8 + t;
        const int ik  = __shfl(myidx, k, 64);
        const int iku = ik < 0 ? 0 : ik;
        const float4 v = *(const float4*)(projb + (size_t)iku * DOUT_ + li * 4);
        mx = fmaxf(mx, ik < 0 ? NEG : v.x);
        my = fmaxf(my, ik < 0 ? NEG : v.y);
        mz = fmaxf(mz, ik < 0 ? NEG : v.z);
        mw = fmaxf(mw, ik < 0 ? NEG : v.w);
    }
#pragma unroll
    for (int off = 16; off < 64; off <<= 1) {
        mx = fmaxf(mx, __shfl_xor(mx, off, 64));
        my = fmaxf(my, __shfl_xor(my, off, 64));
        mz = fmaxf(mz, __shfl_xor(mz, off, 64));
        mw = fmaxf(mw, __shfl_xor(mw, off, 64));
    }

    const int i0 = __shfl(myidx, 0, 64);          // center index, always valid
    if (lane < 16) {
        float4 r = make_float4(mx, my, mz, mw);
        if (ux) {
            const float4 c = *(const float4*)(xp + ((size_t)b * N_ + i0) * DOUT_ + li * 4);
            r.x -= c.x; r.y -= c.y; r.z -= c.z; r.w -= c.w;
        }
        *(float4*)(out + (size_t)pair * DOUT_ + li * 4) = r;
    }
}

// ---------------------------------------------------------------------------
// Fallback (ws too small): fully fused, recomputes projections per gather.
// ---------------------------------------------------------------------------
__global__ __launch_bounds__(256, 1) void fused_fallback_kernel(
    const float* __restrict__ x, const float* __restrict__ xcm,
    const int* __restrict__ indexes,
    const float* __restrict__ w1, const float* __restrict__ w2,
    const float* __restrict__ bias, const int* __restrict__ use_x_p,
    float* __restrict__ out)
{
    const int lane = threadIdx.x & 63;
    const int pair = (blockIdx.x * blockDim.x + threadIdx.x) >> 6;
    const int b    = pair >> 10;
    const int ux   = use_x_p[0];

    float W1[DINC_];
#pragma unroll
    for (int j = 0; j < DINC_; ++j) W1[j] = w1[lane * DINC_ + j];
    float W2[DIN_];
#pragma unroll
    for (int j = 0; j < DIN_; ++j) W2[j] = w2[lane * DIN_ + j];
    const float bv = bias[lane];

    const int* idxp  = indexes + (size_t)pair * K_;
    const int  myidx = idxp[lane & 31];

    const float NEG = -__builtin_inff();
    float m = NEG;
    for (int k = 0; k < K_; ++k) {
        const int ik = __shfl(myidx, k, 64);
        if (ik < 0) continue;
        const float* xc_row = xcm + ((size_t)b * N_ + ik) * DINC_;
        float a1 = bv;
#pragma unroll
        for (int j = 0; j < DINC_; ++j) a1 += xc_row[j] * W1[j];
        if (ux) {
            const float* x_row = x + ((size_t)b * N_ + ik) * DIN_;
            float a2 = 0.f;
#pragma unroll
            for (int j = 0; j < DIN_; ++j) a2 += x_row[j] * W2[j];
            a1 += a2;
        }
        m = fmaxf(m, a1);
    }
    if (ux) {
        const int i0 = __shfl(myidx, 0, 64);
        const float* x_row = x + ((size_t)b * N_ + i0) * DIN_;
        float a2 = 0.f;
#pragma unroll
        for (int j = 0; j < DIN_; ++j) a2 += x_row[j] * W2[j];
        m -= a2;
    }
    out[(size_t)pair * DOUT_ + lane] = m;
}

extern "C" void kernel_launch(void* const* d_in, const int* in_sizes, int n_in,
                              void* d_out, int out_size, void* d_ws, size_t ws_size,
                              hipStream_t stream)
{
    const float* x    = (const float*)d_in[0];
    const float* xcm  = (const float*)d_in[1];
    const int*   idx  = (const int*)d_in[2];
    const float* w1   = (const float*)d_in[3];
    const float* w2   = (const float*)d_in[4];
    const float* bias = (const float*)d_in[5];
    const int*   ux   = (const int*)d_in[6];
    float* out = (float*)d_out;

    const size_t rows    = (size_t)B_ * N_;
    const size_t ws_need = 2 * rows * DOUT_ * sizeof(float);   // proj + xp, 32 MiB
    const int npairs = B_ * S_;                                // 16384

    if (ws_size >= ws_need) {
        float* proj = (float*)d_ws;
        float* xp   = proj + rows * DOUT_;
        // 3072 waves (12/CU with ~150 VGPR): ~21 rows each, 3-deep latency hiding
        proj_kernel<<<768, 256, 0, stream>>>(x, xcm, w1, w2, bias, ux, proj, xp);
        gather_max_kernel<<<npairs / 4, 256, 0, stream>>>(idx, proj, xp, ux, out);
    } else {
        fused_fallback_kernel<<<npairs / 4, 256, 0, stream>>>(x, xcm, idx, w1, w2,
                                                              bias, ux, out);
    }
}

// Round 4
// 132.336 us; speedup vs baseline: 1.1291x; 1.1291x over previous
//
#include <hip/hip_runtime.h>

#define B_    16
#define N_    4096
#define S_    1024
#define K_    32
#define DIN_  64
#define DINC_ 67
#define DOUT_ 64
#define DTOT_ (DINC_ + DIN_)   // 131
#define R_    16               // rows per wave

// ---------------------------------------------------------------------------
// Kernel 1: per-row projection as a register-tiled GEMM.
//   proj[row,c] = bias[c] + dot(xc_row, w1[c,:]) + use_x * dot(x_row, w2[c,:])
//   xp[row,c]   = dot(x_row, w2[c,:])
// Wave = 64 lanes = 64 channels, R_=16 consecutive rows per wave.
// Round-3 lesson: only loop-carried accumulators are guaranteed VGPR-resident.
// So: acc[2][16] in VGPRs; weights streamed from LDS (d-major, lane-stride 1
// -> conflict-free); activations are wave-uniform scalar loads (s_load via
// readfirstlane-derived row pointers) -> scalar cache, off the VALU path.
// ---------------------------------------------------------------------------
__global__ __launch_bounds__(256) void proj_kernel(
    const float* __restrict__ x, const float* __restrict__ xcm,
    const float* __restrict__ w1, const float* __restrict__ w2,
    const float* __restrict__ bias, const int* __restrict__ use_x_p,
    float* __restrict__ proj, float* __restrict__ xp)
{
    __shared__ float lw[DTOT_ * DOUT_];   // lw[d*64 + c], d-major

    for (int i = threadIdx.x; i < DTOT_ * DOUT_; i += 256) {
        const int d = i >> 6, c = i & 63;
        lw[i] = (d < DINC_) ? w1[c * DINC_ + d] : w2[c * DIN_ + (d - DINC_)];
    }
    __syncthreads();

    const int c     = threadIdx.x & 63;
    const int wv_id = __builtin_amdgcn_readfirstlane(threadIdx.x >> 6);
    const int row0  = (blockIdx.x * 4 + wv_id) * R_;
    const int ux    = use_x_p[0];
    const float bv  = bias[c];

    float accA[R_], accB[R_];
#pragma unroll
    for (int r = 0; r < R_; ++r) { accA[r] = 0.f; accB[r] = 0.f; }

    const float* xcb = xcm + (size_t)row0 * DINC_;  // uniform -> s_load base
    const float* xb  = x   + (size_t)row0 * DIN_;   // uniform -> s_load base

#pragma unroll
    for (int d = 0; d < DINC_; ++d) {
        const float wv = lw[d * 64 + c];            // 1 ds_read, stride-1: free
#pragma unroll
        for (int r = 0; r < R_; ++r)
            accA[r] += xcb[r * DINC_ + d] * wv;     // s_act * v_w -> v_fmac
    }
#pragma unroll
    for (int d = 0; d < DIN_; ++d) {
        const float wv = lw[(DINC_ + d) * 64 + c];
#pragma unroll
        for (int r = 0; r < R_; ++r)
            accB[r] += xb[r * DIN_ + d] * wv;
    }

#pragma unroll
    for (int r = 0; r < R_; ++r) {
        const size_t o = (size_t)(row0 + r) * DOUT_ + c;
        xp[o]   = accB[r];
        proj[o] = accA[r] + bv + (ux ? accB[r] : 0.f);
    }
}

// ---------------------------------------------------------------------------
// Kernel 2: gather + masked max + center subtraction.
// One wave per (b,s) pair; lane = channel. The 32 neighbor indices are
// wave-uniform -> scalar loads (no bpermute/shfl at all). Each gather is
// global_load_dword with SGPR row base + lane*4: 256B coalesced, 32
// independent loads in flight. XCD swizzle: blockIdx&7 -> 2 batches per XCD
// (2MB proj slab fits the 4MiB per-XCD L2).
// ---------------------------------------------------------------------------
__global__ __launch_bounds__(256) void gather_max_kernel(
    const int* __restrict__ indexes, const float* __restrict__ proj,
    const float* __restrict__ xp, const int* __restrict__ use_x_p,
    float* __restrict__ out)
{
    const int lane  = threadIdx.x & 63;
    const int wv_id = __builtin_amdgcn_readfirstlane(threadIdx.x >> 6);
    const int xcd   = blockIdx.x & 7;
    const int tb    = blockIdx.x >> 3;
    const int pair  = xcd * ((B_ * S_) / 8) + tb * 4 + wv_id;
    const int b     = pair >> 10;   // S_ = 1024
    const int ux    = use_x_p[0];

    const int*   idxp  = indexes + (size_t)pair * K_;        // uniform -> s_load
    const float* projb = proj + (size_t)b * N_ * DOUT_;

    const float NEG = -__builtin_inff();
    float m = NEG;
#pragma unroll
    for (int k = 0; k < K_; ++k) {
        const int ik  = idxp[k];                             // scalar
        const int iku = ik < 0 ? 0 : ik;
        const float v = projb[(size_t)iku * DOUT_ + lane];   // SGPR base + lane
        m = fmaxf(m, ik < 0 ? NEG : v);
    }
    if (ux) {
        const int i0 = idxp[0];                              // always valid
        m -= xp[((size_t)b * N_ + i0) * DOUT_ + lane];
    }
    out[(size_t)pair * DOUT_ + lane] = m;
}

// ---------------------------------------------------------------------------
// Fallback (ws too small): fully fused, recomputes projections per gather.
// ---------------------------------------------------------------------------
__global__ __launch_bounds__(256, 1) void fused_fallback_kernel(
    const float* __restrict__ x, const float* __restrict__ xcm,
    const int* __restrict__ indexes,
    const float* __restrict__ w1, const float* __restrict__ w2,
    const float* __restrict__ bias, const int* __restrict__ use_x_p,
    float* __restrict__ out)
{
    const int lane = threadIdx.x & 63;
    const int pair = (blockIdx.x * blockDim.x + threadIdx.x) >> 6;
    const int b    = pair >> 10;
    const int ux   = use_x_p[0];

    float W1[DINC_];
#pragma unroll
    for (int j = 0; j < DINC_; ++j) W1[j] = w1[lane * DINC_ + j];
    float W2[DIN_];
#pragma unroll
    for (int j = 0; j < DIN_; ++j) W2[j] = w2[lane * DIN_ + j];
    const float bv = bias[lane];

    const int* idxp  = indexes + (size_t)pair * K_;
    const int  myidx = idxp[lane & 31];

    const float NEG = -__builtin_inff();
    float m = NEG;
    for (int k = 0; k < K_; ++k) {
        const int ik = __shfl(myidx, k, 64);
        if (ik < 0) continue;
        const float* xc_row = xcm + ((size_t)b * N_ + ik) * DINC_;
        float a1 = bv;
#pragma unroll
        for (int j = 0; j < DINC_; ++j) a1 += xc_row[j] * W1[j];
        if (ux) {
            const float* x_row = x + ((size_t)b * N_ + ik) * DIN_;
            float a2 = 0.f;
#pragma unroll
            for (int j = 0; j < DIN_; ++j) a2 += x_row[j] * W2[j];
            a1 += a2;
        }
        m = fmaxf(m, a1);
    }
    if (ux) {
        const int i0 = __shfl(myidx, 0, 64);
        const float* x_row = x + ((size_t)b * N_ + i0) * DIN_;
        float a2 = 0.f;
#pragma unroll
        for (int j = 0; j < DIN_; ++j) a2 += x_row[j] * W2[j];
        m -= a2;
    }
    out[(size_t)pair * DOUT_ + lane] = m;
}

extern "C" void kernel_launch(void* const* d_in, const int* in_sizes, int n_in,
                              void* d_out, int out_size, void* d_ws, size_t ws_size,
                              hipStream_t stream)
{
    const float* x    = (const float*)d_in[0];
    const float* xcm  = (const float*)d_in[1];
    const int*   idx  = (const int*)d_in[2];
    const float* w1   = (const float*)d_in[3];
    const float* w2   = (const float*)d_in[4];
    const float* bias = (const float*)d_in[5];
    const int*   ux   = (const int*)d_in[6];
    float* out = (float*)d_out;

    const size_t rows    = (size_t)B_ * N_;
    const size_t ws_need = 2 * rows * DOUT_ * sizeof(float);   // proj + xp, 32 MiB
    const int npairs = B_ * S_;                                // 16384

    if (ws_size >= ws_need) {
        float* proj = (float*)d_ws;
        float* xp   = proj + rows * DOUT_;
        // 1024 blocks x 4 waves x 16 rows = 65536 rows, exact cover
        proj_kernel<<<(int)(rows / (4 * R_)), 256, 0, stream>>>(x, xcm, w1, w2,
                                                                bias, ux, proj, xp);
        gather_max_kernel<<<npairs / 4, 256, 0, stream>>>(idx, proj, xp, ux, out);
    } else {
        fused_fallback_kernel<<<npairs / 4, 256, 0, stream>>>(x, xcm, idx, w1, w2,
                                                              bias, ux, out);
    }
}